// Round 1
// 307.834 us; speedup vs baseline: 1.1064x; 1.1064x over previous
//
#include <hip/hip_runtime.h>

// Problem constants: B=2, S=2048, IN=4096, OUT=4096, RANK=8, LORA_R=16
#define M_DIM 4096
#define IN_DIM 4096
#define OUT_DIM 4096
#define RANK 8
#define LORA_R 16
#define LORA_SCALING 1.0f

typedef __bf16 bf16;
typedef bf16  bf16x4 __attribute__((ext_vector_type(4)));
typedef bf16  bf16x8 __attribute__((ext_vector_type(8)));
typedef float f32x4  __attribute__((ext_vector_type(4)));
typedef float f32x16 __attribute__((ext_vector_type(16)));

// -------------------------------------------------------------------------
// Kernel 1 (fused): blocks [0,2048) fold weight; blocks [2048,4096) cast x.
// UNCHANGED this round (isolating the GEMM restructure).
// -------------------------------------------------------------------------
#define OG 8
__global__ __launch_bounds__(256) void prep_fused(
    const float* __restrict__ weight, const float* __restrict__ scale_A,
    const float* __restrict__ scale_B, const float* __restrict__ g,
    const float* __restrict__ lora_A, const float* __restrict__ lora_B,
    const float* __restrict__ x, bf16* __restrict__ wt, bf16* __restrict__ xb)
{
    const int t = threadIdx.x;
    if (blockIdx.x < 2048) {
        __shared__ float s_sa[OG][RANK];
        __shared__ float s_lb[OG][LORA_R];
        const int o0 = (blockIdx.x >> 2) * OG;
        if (t < OG * RANK) {
            int r8 = t / RANK, k = t % RANK;
            s_sa[r8][k] = scale_A[(o0 + r8) * RANK + k] * g[k];
        }
        if (t < OG * LORA_R) {
            int r8 = t / LORA_R, r = t % LORA_R;
            s_lb[r8][r] = lora_B[(o0 + r8) * LORA_R + r] * LORA_SCALING;
        }
        __syncthreads();

        const int i0 = ((blockIdx.x & 3) * 256 + t) * 4;

        f32x4 acc[OG];
#pragma unroll
        for (int r8 = 0; r8 < OG; ++r8) acc[r8] = {0.f, 0.f, 0.f, 0.f};
#pragma unroll
        for (int k = 0; k < RANK; ++k) {
            f32x4 sbk = *(const f32x4*)(scale_B + k * IN_DIM + i0);
#pragma unroll
            for (int r8 = 0; r8 < OG; ++r8) acc[r8] += s_sa[r8][k] * sbk;
        }
#pragma unroll
        for (int r8 = 0; r8 < OG; ++r8) {
            f32x4 wv = *(const f32x4*)(weight + (size_t)(o0 + r8) * IN_DIM + i0);
            acc[r8] *= wv;
        }
#pragma unroll
        for (int r = 0; r < LORA_R; ++r) {
            f32x4 lak = *(const f32x4*)(lora_A + r * IN_DIM + i0);
#pragma unroll
            for (int r8 = 0; r8 < OG; ++r8) acc[r8] += s_lb[r8][r] * lak;
        }
#pragma unroll
        for (int r8 = 0; r8 < OG; ++r8) {
            bf16x4 h = { (bf16)acc[r8][0], (bf16)acc[r8][1],
                         (bf16)acc[r8][2], (bf16)acc[r8][3] };
            *(bf16x4*)(wt + (size_t)(o0 + r8) * IN_DIM + i0) = h;
        }
    } else {
        const int n4  = (M_DIM * IN_DIM) / 4;
        int idx    = (blockIdx.x - 2048) * 256 + t;
        int stride = 2048 * 256;
        for (int i = idx; i < n4; i += stride) {
            f32x4 v = *(const f32x4*)(x + (size_t)i * 4);
            bf16x4 h = { (bf16)v[0], (bf16)v[1], (bf16)v[2], (bf16)v[3] };
            *(bf16x4*)(xb + (size_t)i * 4) = h;
        }
    }
}

// -------------------------------------------------------------------------
// Kernel 2: 256x256 tile, BK=64, 8 waves (2Mx4N), 128 KiB LDS double-buffer.
// 4 phases per K-tile: {ds_read subtile || stage 1 half-tile -> barrier ->
// lgkmcnt(0) -> setprio(1) -> 8 MFMA -> setprio(0) -> barrier}, counted
// vmcnt(4) once per tile (phase 4) -- never 0 in the main loop.
//
// LDS map (bytes): A: buf p at p*32768, kh at +kh*16384, row*64 + chunk*16
//                  B: same, +65536.  Half-tile = 256 rows x 32 cols bf16.
// K-half phase order: ph1/ph2 consume kh0, ph3/ph4 consume kh1.
//   -> kh0(buf p) dead after ph2's close barrier, kh1 dead after ph4's.
// Stage schedule: ph1: A-kh1(t+1) -> buf p^1  (dead since t-1 ph4)
//                 ph2: B-kh1(t+1) -> buf p^1
//                 ph3: A-kh0(t+2) -> buf p    (kh0 died at ph2 close)
//                 ph4: B-kh0(t+2) -> buf p
// vmcnt(4) at ph4 leaves exactly the two kh0(t+2) half-tiles (4 loads) in
// flight and guarantees kh0(t+1) [staged t-1 ph3/4] and kh1(t+1) [t ph1/2]
// are complete before any tile-(t+1) ds_read.
//
// Swizzle (both-sides involution, rule #21): chunk position in LDS row =
// c ^ ((row>>1)&3).  Stage side pre-swizzles the GLOBAL source (LDS dest
// stays linear for global_load_lds); read side applies the same XOR.
// -------------------------------------------------------------------------
#define BM 256
#define BN 256
#define BK 64

__device__ __forceinline__ void gload16(const bf16* g, bf16* l) {
    __builtin_amdgcn_global_load_lds(
        (const __attribute__((address_space(1))) void*)g,
        (__attribute__((address_space(3))) void*)l,
        16, 0, 0);
}

#define MFMA(d, a, b) d = __builtin_amdgcn_mfma_f32_32x32x16_bf16((a), (b), (d), 0, 0, 0)
#define BARRIER() __builtin_amdgcn_s_barrier()
#define WAIT_LGKM0() asm volatile("s_waitcnt lgkmcnt(0)" ::: "memory")
#define WAIT_VM(n)   asm volatile("s_waitcnt vmcnt(" #n ")" ::: "memory")

__global__ __launch_bounds__(512, 2) void gemm_bt(
    const bf16* __restrict__ A,   // [4096,4096] bf16 row-major (x)
    const bf16* __restrict__ Bw,  // [4096,4096] bf16 row-major (W_eff, B^T)
    float* __restrict__ C)        // [4096,4096] fp32 row-major
{
    __shared__ __align__(16) char smem[131072];

    const int t  = threadIdx.x;
    const int w  = t >> 6;        // wave 0..7
    const int l  = t & 63;
    const int lh = l >> 5;
    const int ln = l & 31;
    const int wm = w >> 2;        // 0..1 -> M offset wm*128
    const int wn = w & 3;         // 0..3 -> N offset wn*64

    // XCD-compact block mapping: 256 blocks = 8 XCDs x (4M x 8N) tile chunk.
    const int bid = blockIdx.x;
    const int xcd = bid & 7;
    const int loc = bid >> 3;                      // 0..31
    const int mt  = (xcd & 3) * 4 + (loc >> 3);    // 0..15
    const int nt  = (xcd >> 2) * 8 + (loc & 7);    // 0..15
    const int m0  = mt * BM;
    const int n0  = nt * BN;

    // ---- staging source (per lane): wave-load covers 16 rows x 64B.
    // LDS slot (row, pos) receives global chunk  c = pos ^ ((row>>1)&3).
    const int srow   = l >> 2;                        // 0..15
    const int schunk = (l & 3) ^ ((l >> 3) & 3);      // pre-swizzled source chunk
    const size_t soff = (size_t)(w * 16 + srow) * IN_DIM + schunk * 8;
    const bf16* gA = A  + (size_t)m0 * IN_DIM + soff;
    const bf16* gB = Bw + (size_t)n0 * IN_DIM + soff;
    const int wA = w << 10;                           // wave's 1KB LDS slot (j=0)

#define STAGE(gsrc, dstbyte) do {                                   \
        bf16* d_ = (bf16*)(smem + (dstbyte));                       \
        gload16((gsrc), d_);                                        \
        gload16((gsrc) + (size_t)128 * IN_DIM, d_ + 4096);          \
    } while (0)

    // ---- ds_read bases: frag (row, kc) at row*64 + ((c)^((row>>1)&3))*16,
    // c = (kc&1)*2 + lh.  (row>>1)&3 == (ln>>1)&3 (row-base multiples of 32).
    const int s4  = (ln >> 1) & 3;
    const int cEv = ((lh)     ^ s4) << 4;
    const int cOd = ((2 + lh) ^ s4) << 4;
    const char* aB0 = smem + (wm * 128 + ln) * 64;
    const char* bB0 = smem + 65536 + (wn * 64 + ln) * 64;

    f32x16 acc[4][2] = {};

    // ---- prologue: kh0(0), kh1(0), kh0(1); keep kh0(1) (4 loads) in flight.
    STAGE(gA + 0,  0      + wA);
    STAGE(gB + 0,  65536  + wA);
    STAGE(gA + 32, 16384  + wA);
    STAGE(gB + 32, 65536 + 16384 + wA);
    STAGE(gA + 64, 32768  + wA);
    STAGE(gB + 64, 65536 + 32768 + wA);
    WAIT_VM(4);
    BARRIER();

#pragma unroll 2
    for (int kt = 0; kt < 64; ++kt) {
        const int p   = kt & 1;
        const int po  = p << 15;          // this tile's buffer
        const int qo  = po ^ 32768;       // other buffer
        const int kc1 = (kt + 1 < 64) ? (kt + 1) * BK : 0;   // clamped
        const int kc2 = (kt + 2 < 64) ? (kt + 2) * BK : 0;   // clamped

        // ================= phase 1: kh0, M0/M1 x N0/N1 =================
        bf16x8 a00 = *(const bf16x8*)(aB0 + po + cEv);
        bf16x8 a01 = *(const bf16x8*)(aB0 + po + cOd);
        bf16x8 a10 = *(const bf16x8*)(aB0 + po + 2048 + cEv);
        bf16x8 a11 = *(const bf16x8*)(aB0 + po + 2048 + cOd);
        bf16x8 b00 = *(const bf16x8*)(bB0 + po + cEv);
        bf16x8 b01 = *(const bf16x8*)(bB0 + po + cOd);
        bf16x8 b10 = *(const bf16x8*)(bB0 + po + 2048 + cEv);
        bf16x8 b11 = *(const bf16x8*)(bB0 + po + 2048 + cOd);
        STAGE(gA + kc1 + 32, qo + 16384 + wA);          // A-kh1(t+1)
        BARRIER();
        WAIT_LGKM0();
        __builtin_amdgcn_s_setprio(1);
        MFMA(acc[0][0], a00, b00); MFMA(acc[0][1], a00, b10);
        MFMA(acc[1][0], a10, b00); MFMA(acc[1][1], a10, b10);
        MFMA(acc[0][0], a01, b01); MFMA(acc[0][1], a01, b11);
        MFMA(acc[1][0], a11, b01); MFMA(acc[1][1], a11, b11);
        __builtin_amdgcn_s_setprio(0);
        BARRIER();

        // ================= phase 2: kh0, M2/M3 (B frags reused) =========
        bf16x8 a20 = *(const bf16x8*)(aB0 + po + 4096 + cEv);
        bf16x8 a21 = *(const bf16x8*)(aB0 + po + 4096 + cOd);
        bf16x8 a30 = *(const bf16x8*)(aB0 + po + 6144 + cEv);
        bf16x8 a31 = *(const bf16x8*)(aB0 + po + 6144 + cOd);
        STAGE(gB + kc1 + 32, 65536 + qo + 16384 + wA);  // B-kh1(t+1)
        BARRIER();
        WAIT_LGKM0();
        __builtin_amdgcn_s_setprio(1);
        MFMA(acc[2][0], a20, b00); MFMA(acc[2][1], a20, b10);
        MFMA(acc[3][0], a30, b00); MFMA(acc[3][1], a30, b10);
        MFMA(acc[2][0], a21, b01); MFMA(acc[2][1], a21, b11);
        MFMA(acc[3][0], a31, b01); MFMA(acc[3][1], a31, b11);
        __builtin_amdgcn_s_setprio(0);
        BARRIER();

        // ================= phase 3: kh1, M0/M1 (kh0 now dead) ===========
        a00 = *(const bf16x8*)(aB0 + po + 16384 + cEv);
        a01 = *(const bf16x8*)(aB0 + po + 16384 + cOd);
        a10 = *(const bf16x8*)(aB0 + po + 16384 + 2048 + cEv);
        a11 = *(const bf16x8*)(aB0 + po + 16384 + 2048 + cOd);
        b00 = *(const bf16x8*)(bB0 + po + 16384 + cEv);
        b01 = *(const bf16x8*)(bB0 + po + 16384 + cOd);
        b10 = *(const bf16x8*)(bB0 + po + 16384 + 2048 + cEv);
        b11 = *(const bf16x8*)(bB0 + po + 16384 + 2048 + cOd);
        STAGE(gA + kc2, po + wA);                       // A-kh0(t+2)
        BARRIER();
        WAIT_LGKM0();
        __builtin_amdgcn_s_setprio(1);
        MFMA(acc[0][0], a00, b00); MFMA(acc[0][1], a00, b10);
        MFMA(acc[1][0], a10, b00); MFMA(acc[1][1], a10, b10);
        MFMA(acc[0][0], a01, b01); MFMA(acc[0][1], a01, b11);
        MFMA(acc[1][0], a11, b01); MFMA(acc[1][1], a11, b11);
        __builtin_amdgcn_s_setprio(0);
        BARRIER();

        // ================= phase 4: kh1, M2/M3 + vmcnt(4) ===============
        a20 = *(const bf16x8*)(aB0 + po + 16384 + 4096 + cEv);
        a21 = *(const bf16x8*)(aB0 + po + 16384 + 4096 + cOd);
        a30 = *(const bf16x8*)(aB0 + po + 16384 + 6144 + cEv);
        a31 = *(const bf16x8*)(aB0 + po + 16384 + 6144 + cOd);
        STAGE(gB + kc2, 65536 + po + wA);               // B-kh0(t+2)
        BARRIER();
        WAIT_LGKM0();
        __builtin_amdgcn_s_setprio(1);
        MFMA(acc[2][0], a20, b00); MFMA(acc[2][1], a20, b10);
        MFMA(acc[3][0], a30, b00); MFMA(acc[3][1], a30, b10);
        MFMA(acc[2][0], a21, b01); MFMA(acc[2][1], a21, b11);
        MFMA(acc[3][0], a31, b01); MFMA(acc[3][1], a31, b11);
        __builtin_amdgcn_s_setprio(0);
        WAIT_VM(4);        // counted: only kh0(t+2)'s 4 loads stay in flight
        BARRIER();
    }

    // ---- epilogue: drain, then LDS transpose (stride 33) -> dwordx4 stores.
    asm volatile("s_waitcnt vmcnt(0) lgkmcnt(0)" ::: "memory");
    BARRIER();
    float* sEw = (float*)(void*)smem + w * (32 * 33);
#pragma unroll
    for (int tm2 = 0; tm2 < 4; ++tm2)
#pragma unroll
        for (int tn2 = 0; tn2 < 2; ++tn2) {
            // C/D layout (m74/m101): col = ln, row = (j&3) + 8*(j>>2) + 4*lh
#pragma unroll
            for (int j = 0; j < 16; ++j) {
                int row = (j & 3) + 8 * (j >> 2) + 4 * lh;
                sEw[row * 33 + ln] = acc[tm2][tn2][j];
            }
#pragma unroll
            for (int q = 0; q < 4; ++q) {
                int r4 = q * 8 + (l >> 3);
                int c4 = (l & 7) * 4;
                f32x4 v = { sEw[r4 * 33 + c4],     sEw[r4 * 33 + c4 + 1],
                            sEw[r4 * 33 + c4 + 2], sEw[r4 * 33 + c4 + 3] };
                *(f32x4*)(C + (size_t)(m0 + wm * 128 + tm2 * 32 + r4) * OUT_DIM
                            + (n0 + wn * 64 + tn2 * 32 + c4)) = v;
            }
        }
}

// -------------------------------------------------------------------------
extern "C" void kernel_launch(void* const* d_in, const int* in_sizes, int n_in,
                              void* d_out, int out_size, void* d_ws, size_t ws_size,
                              hipStream_t stream) {
    (void)in_sizes; (void)n_in; (void)out_size; (void)ws_size;
    const float* x        = (const float*)d_in[0];
    const float* weight   = (const float*)d_in[1];
    const float* scale_A  = (const float*)d_in[2];
    const float* scale_B  = (const float*)d_in[3];
    const float* g        = (const float*)d_in[4];
    const float* lora_A   = (const float*)d_in[5];
    const float* lora_B   = (const float*)d_in[6];
    float* out = (float*)d_out;

    bf16* xb = (bf16*)d_ws;
    bf16* wt = (bf16*)((char*)d_ws + (size_t)M_DIM * IN_DIM * sizeof(bf16));

    prep_fused<<<4096, 256, 0, stream>>>(weight, scale_A, scale_B, g,
                                         lora_A, lora_B, x, wt, xb);

    gemm_bt<<<(M_DIM / BM) * (OUT_DIM / BN), 512, 0, stream>>>(xb, wt, out);
}

// Round 2
// 301.291 us; speedup vs baseline: 1.1304x; 1.0217x over previous
//
#include <hip/hip_runtime.h>

// Problem constants: B=2, S=2048, IN=4096, OUT=4096, RANK=8, LORA_R=16
#define M_DIM 4096
#define IN_DIM 4096
#define OUT_DIM 4096
#define RANK 8
#define LORA_R 16
#define LORA_SCALING 1.0f

typedef __bf16 bf16;
typedef bf16  bf16x4 __attribute__((ext_vector_type(4)));
typedef bf16  bf16x8 __attribute__((ext_vector_type(8)));
typedef float f32x4  __attribute__((ext_vector_type(4)));

// -------------------------------------------------------------------------
// Kernel 1 (fused): blocks [0,2048) fold weight; blocks [2048,4096) cast x.
// UNCHANGED (isolating the GEMM restructure).
// -------------------------------------------------------------------------
#define OG 8
__global__ __launch_bounds__(256) void prep_fused(
    const float* __restrict__ weight, const float* __restrict__ scale_A,
    const float* __restrict__ scale_B, const float* __restrict__ g,
    const float* __restrict__ lora_A, const float* __restrict__ lora_B,
    const float* __restrict__ x, bf16* __restrict__ wt, bf16* __restrict__ xb)
{
    const int t = threadIdx.x;
    if (blockIdx.x < 2048) {
        __shared__ float s_sa[OG][RANK];
        __shared__ float s_lb[OG][LORA_R];
        const int o0 = (blockIdx.x >> 2) * OG;
        if (t < OG * RANK) {
            int r8 = t / RANK, k = t % RANK;
            s_sa[r8][k] = scale_A[(o0 + r8) * RANK + k] * g[k];
        }
        if (t < OG * LORA_R) {
            int r8 = t / LORA_R, r = t % LORA_R;
            s_lb[r8][r] = lora_B[(o0 + r8) * LORA_R + r] * LORA_SCALING;
        }
        __syncthreads();

        const int i0 = ((blockIdx.x & 3) * 256 + t) * 4;

        f32x4 acc[OG];
#pragma unroll
        for (int r8 = 0; r8 < OG; ++r8) acc[r8] = {0.f, 0.f, 0.f, 0.f};
#pragma unroll
        for (int k = 0; k < RANK; ++k) {
            f32x4 sbk = *(const f32x4*)(scale_B + k * IN_DIM + i0);
#pragma unroll
            for (int r8 = 0; r8 < OG; ++r8) acc[r8] += s_sa[r8][k] * sbk;
        }
#pragma unroll
        for (int r8 = 0; r8 < OG; ++r8) {
            f32x4 wv = *(const f32x4*)(weight + (size_t)(o0 + r8) * IN_DIM + i0);
            acc[r8] *= wv;
        }
#pragma unroll
        for (int r = 0; r < LORA_R; ++r) {
            f32x4 lak = *(const f32x4*)(lora_A + r * IN_DIM + i0);
#pragma unroll
            for (int r8 = 0; r8 < OG; ++r8) acc[r8] += s_lb[r8][r] * lak;
        }
#pragma unroll
        for (int r8 = 0; r8 < OG; ++r8) {
            bf16x4 h = { (bf16)acc[r8][0], (bf16)acc[r8][1],
                         (bf16)acc[r8][2], (bf16)acc[r8][3] };
            *(bf16x4*)(wt + (size_t)(o0 + r8) * IN_DIM + i0) = h;
        }
    } else {
        const int n4  = (M_DIM * IN_DIM) / 4;
        int idx    = (blockIdx.x - 2048) * 256 + t;
        int stride = 2048 * 256;
        for (int i = idx; i < n4; i += stride) {
            f32x4 v = *(const f32x4*)(x + (size_t)i * 4);
            bf16x4 h = { (bf16)v[0], (bf16)v[1], (bf16)v[2], (bf16)v[3] };
            *(bf16x4*)(xb + (size_t)i * 4) = h;
        }
    }
}

// -------------------------------------------------------------------------
// Kernel 2: m201-geometry port. 256x256 tile, BK=64, 8 waves (2Mx4N),
// MFMA 16x16x32, LDS halves [128 rows][128B] with st_16x32 swizzle
// (byte ^= ((byte>>9)&1)<<5  ==  16B-slot ^= ((row>>2)&1)<<1).
//
// LDS map (bytes), buffer p at p*65536:
//   A-half h: p*65536 + h*16384          (rows h*128..+127 of the A tile)
//   B-half h: p*65536 + 32768 + h*16384
//
// Phases = GLOBAL C-quadrants (all 8 waves on one 128x128 quadrant,
// per-wave 64x32, 16 MFMA): ph1 (qm0,qn0), ph2 (0,1), ph3 (1,1), ph4 (1,0).
// A-frags reused ph1->ph2 and ph3->ph4; B-frags ph2->ph3. 28 ds_reads/kt.
//
// Stage schedule (tile t+1 -> other buffer, fully dead during t):
//   ph1: A-h0, ph2: B-h0, ph3: B-h1, ph4: A-h1   (2 gloads each)
// Uniform vmcnt(4) at EVERY phase close (4 loads always in flight, never 0):
//   t.ph4  close -> t.ph1/ph2 stages landed -> t+1.ph1 reads A-h0,B-h0 safe
//   t+1.ph1 close -> t.ph3 landed           -> t+1.ph2 reads B-h1 safe
//   t+1.ph2 close -> t.ph4 landed           -> t+1.ph3 reads A-h1 safe
//
// Swizzle both-sides involution (rule #21): gload dest LINEAR; global
// SOURCE pre-swizzled: lane l fetches chunk (l&7) ^ (((l>>5)&1)<<1) of its
// row; ds_read applies slot = (ks*4 + (l>>4)) ^ (((l>>2)&1)<<1).
// -------------------------------------------------------------------------
#define BM 256
#define BN 256
#define BK 64

__device__ __forceinline__ void gload16(const bf16* g, bf16* l) {
    __builtin_amdgcn_global_load_lds(
        (const __attribute__((address_space(1))) void*)g,
        (__attribute__((address_space(3))) void*)l,
        16, 0, 0);
}

#define BARRIER()    __builtin_amdgcn_s_barrier()
#define WAIT_LGKM0() asm volatile("s_waitcnt lgkmcnt(0)" ::: "memory")
#define WAIT_VM(n)   asm volatile("s_waitcnt vmcnt(" #n ")" ::: "memory")

__device__ __forceinline__ void load_af(bf16x8 (&aF)[4][2], const char* aB, int off) {
#pragma unroll
    for (int r = 0; r < 4; ++r)
#pragma unroll
        for (int ks = 0; ks < 2; ++ks)
            aF[r][ks] = *(const bf16x8*)(aB + off + r * 2048 + ks * 64);
}
__device__ __forceinline__ void load_bf(bf16x8 (&bF)[2][2], const char* bB, int off) {
#pragma unroll
    for (int n = 0; n < 2; ++n)
#pragma unroll
        for (int ks = 0; ks < 2; ++ks)
            bF[n][ks] = *(const bf16x8*)(bB + off + n * 2048 + ks * 64);
}

template<int QM, int QN>
__device__ __forceinline__ void mfma_quad(f32x4 (&acc)[2][2][4][2],
                                          const bf16x8 (&aF)[4][2],
                                          const bf16x8 (&bF)[2][2]) {
#pragma unroll
    for (int ks = 0; ks < 2; ++ks)
#pragma unroll
        for (int r = 0; r < 4; ++r)
#pragma unroll
            for (int n = 0; n < 2; ++n)
                acc[QM][QN][r][n] = __builtin_amdgcn_mfma_f32_16x16x32_bf16(
                    aF[r][ks], bF[n][ks], acc[QM][QN][r][n], 0, 0, 0);
}

__global__ __launch_bounds__(512, 2) void gemm_bt(
    const bf16* __restrict__ A,   // [4096,4096] bf16 row-major (x)
    const bf16* __restrict__ Bw,  // [4096,4096] bf16 row-major (W_eff, B^T)
    float* __restrict__ C)        // [4096,4096] fp32 row-major
{
    __shared__ __align__(16) char smem[131072];

    const int t  = threadIdx.x;
    const int w  = t >> 6;        // wave 0..7
    const int l  = t & 63;
    const int wm = w >> 2;        // 0..1 -> wave M offset within quadrant: wm*64
    const int wn = w & 3;         // 0..3 -> wave N offset within quadrant: wn*32

    // XCD-compact block mapping: 256 blocks = 8 XCDs x (4M x 8N) tile chunk.
    const int bid = blockIdx.x;
    const int xcd = bid & 7;
    const int loc = bid >> 3;                      // 0..31
    const int mt  = (xcd & 3) * 4 + (loc >> 3);    // 0..15
    const int nt  = (xcd >> 2) * 8 + (loc & 7);    // 0..15
    const int m0  = mt * BM;
    const int n0  = nt * BN;

    // ---- staging (per lane): gload round j covers rows j*64 + w*8 + (l>>3).
    // Pre-swizzled global source chunk: (l&7) ^ (((l>>5)&1)<<1).
    const int scol = 8 * ((l & 7) ^ (((l >> 5) & 1) << 1));
    const bf16* gAs = A  + (size_t)(m0 + w * 8 + (l >> 3)) * IN_DIM + scol;
    const bf16* gBs = Bw + (size_t)(n0 + w * 8 + (l >> 3)) * IN_DIM + scol;

#define STAGEH(gbase, kc, dstOff) do {                                        \
        gload16((gbase) + (kc),                                               \
                (bf16*)(smem + (dstOff) + (w << 10)));                        \
        gload16((gbase) + (kc) + (size_t)64 * IN_DIM,                         \
                (bf16*)(smem + (dstOff) + 8192 + (w << 10)));                 \
    } while (0)

    // ---- ds_read bases: frag (row=rowbase+(l&15), slot=(ks*4+(l>>4))^sw).
    const int fr  = l & 15;
    const int sw2 = ((l >> 2) & 1) << 1;
    const int sl0 = (((l >> 4) & 3) ^ sw2) << 4;     // kstep0 slot byte (kstep1: +64)
    const char* aB = smem + wm * 8192 + fr * 128 + sl0;            // + po + QM*16384
    const char* bB = smem + 32768 + wn * 4096 + fr * 128 + sl0;    // + po + QN*16384

    f32x4 acc[2][2][4][2] = {};
    bf16x8 aF[4][2], bF[2][2];

    // ---- prologue: tile 0's halves in deadline order; keep last 4 in flight.
    STAGEH(gAs, 0, 0);                                   // A-h0(0)
    STAGEH(gBs, 0, 32768);                               // B-h0(0)
    STAGEH(gBs + (size_t)128 * IN_DIM, 0, 49152);        // B-h1(0)
    STAGEH(gAs + (size_t)128 * IN_DIM, 0, 16384);        // A-h1(0)
    WAIT_VM(4);
    BARRIER();

#pragma unroll 2
    for (int kt = 0; kt < 64; ++kt) {
        const int po  = (kt & 1) << 16;
        const int qo  = po ^ 65536;
        const int kcn = (kt + 1 < 64) ? (kt + 1) * BK : 0;   // clamped (bf16 cols)

        // ===== phase 1: quadrant (0,0) =====
        load_af(aF, aB, po);
        load_bf(bF, bB, po);
        STAGEH(gAs, kcn, qo);                            // A-h0(t+1)
        BARRIER();
        WAIT_LGKM0();
        __builtin_amdgcn_s_setprio(1);
        mfma_quad<0, 0>(acc, aF, bF);
        __builtin_amdgcn_s_setprio(0);
        WAIT_VM(4);
        BARRIER();

        // ===== phase 2: quadrant (0,1) — A-frags reused =====
        load_bf(bF, bB, po + 16384);
        STAGEH(gBs, kcn, qo + 32768);                    // B-h0(t+1)
        BARRIER();
        WAIT_LGKM0();
        __builtin_amdgcn_s_setprio(1);
        mfma_quad<0, 1>(acc, aF, bF);
        __builtin_amdgcn_s_setprio(0);
        WAIT_VM(4);
        BARRIER();

        // ===== phase 3: quadrant (1,1) — B-frags reused =====
        load_af(aF, aB, po + 16384);
        STAGEH(gBs + (size_t)128 * IN_DIM, kcn, qo + 49152);   // B-h1(t+1)
        BARRIER();
        WAIT_LGKM0();
        __builtin_amdgcn_s_setprio(1);
        mfma_quad<1, 1>(acc, aF, bF);
        __builtin_amdgcn_s_setprio(0);
        WAIT_VM(4);
        BARRIER();

        // ===== phase 4: quadrant (1,0) — A-frags reused =====
        load_bf(bF, bB, po);
        STAGEH(gAs + (size_t)128 * IN_DIM, kcn, qo + 16384);   // A-h1(t+1)
        BARRIER();
        WAIT_LGKM0();
        __builtin_amdgcn_s_setprio(1);
        mfma_quad<1, 0>(acc, aF, bF);
        __builtin_amdgcn_s_setprio(0);
        WAIT_VM(4);
        BARRIER();
    }

    // ---- epilogue: drain, then per-wave LDS transpose (stride 33) ----
    asm volatile("s_waitcnt vmcnt(0) lgkmcnt(0)" ::: "memory");
    BARRIER();
    float* sE = (float*)(void*)smem + w * (64 * 33);   // 8448B/wave * 8 = 67.6KB
    const int er = l >> 4;        // 0..3
    const int ec = l & 15;
#pragma unroll
    for (int QM = 0; QM < 2; ++QM)
#pragma unroll
        for (int QN = 0; QN < 2; ++QN) {
            // C/D layout (m89/m91): col = l&15, row = (l>>4)*4 + j
#pragma unroll
            for (int r = 0; r < 4; ++r)
#pragma unroll
                for (int n = 0; n < 2; ++n)
#pragma unroll
                    for (int j = 0; j < 4; ++j)
                        sE[(r * 16 + er * 4 + j) * 33 + n * 16 + ec] =
                            acc[QM][QN][r][n][j];
#pragma unroll
            for (int q = 0; q < 8; ++q) {
                int r2 = q * 8 + (l >> 3);
                int c2 = (l & 7) * 4;
                f32x4 v = { sE[r2 * 33 + c2],     sE[r2 * 33 + c2 + 1],
                            sE[r2 * 33 + c2 + 2], sE[r2 * 33 + c2 + 3] };
                *(f32x4*)(C + (size_t)(m0 + QM * 128 + wm * 64 + r2) * OUT_DIM
                            + (n0 + QN * 128 + wn * 32 + c2)) = v;
            }
        }
}

// -------------------------------------------------------------------------
extern "C" void kernel_launch(void* const* d_in, const int* in_sizes, int n_in,
                              void* d_out, int out_size, void* d_ws, size_t ws_size,
                              hipStream_t stream) {
    (void)in_sizes; (void)n_in; (void)out_size; (void)ws_size;
    const float* x        = (const float*)d_in[0];
    const float* weight   = (const float*)d_in[1];
    const float* scale_A  = (const float*)d_in[2];
    const float* scale_B  = (const float*)d_in[3];
    const float* g        = (const float*)d_in[4];
    const float* lora_A   = (const float*)d_in[5];
    const float* lora_B   = (const float*)d_in[6];
    float* out = (float*)d_out;

    bf16* xb = (bf16*)d_ws;
    bf16* wt = (bf16*)((char*)d_ws + (size_t)M_DIM * IN_DIM * sizeof(bf16));

    prep_fused<<<4096, 256, 0, stream>>>(weight, scale_A, scale_B, g,
                                         lora_A, lora_B, x, wt, xb);

    gemm_bt<<<(M_DIM / BM) * (OUT_DIM / BN), 512, 0, stream>>>(xb, wt, out);
}

// Round 3
// 289.031 us; speedup vs baseline: 1.1784x; 1.0424x over previous
//
#include <hip/hip_runtime.h>

// Problem constants: B=2, S=2048, IN=4096, OUT=4096, RANK=8, LORA_R=16
#define M_DIM 4096
#define IN_DIM 4096
#define OUT_DIM 4096
#define RANK 8
#define LORA_R 16
#define LORA_SCALING 1.0f

typedef __bf16 bf16;
typedef bf16  bf16x4 __attribute__((ext_vector_type(4)));
typedef bf16  bf16x8 __attribute__((ext_vector_type(8)));
typedef float f32x4  __attribute__((ext_vector_type(4)));

// -------------------------------------------------------------------------
// Kernel 1 (fused): blocks [0,2048) fold weight; blocks [2048,4096) cast x.
// UNCHANGED.
// -------------------------------------------------------------------------
#define OG 8
__global__ __launch_bounds__(256) void prep_fused(
    const float* __restrict__ weight, const float* __restrict__ scale_A,
    const float* __restrict__ scale_B, const float* __restrict__ g,
    const float* __restrict__ lora_A, const float* __restrict__ lora_B,
    const float* __restrict__ x, bf16* __restrict__ wt, bf16* __restrict__ xb)
{
    const int t = threadIdx.x;
    if (blockIdx.x < 2048) {
        __shared__ float s_sa[OG][RANK];
        __shared__ float s_lb[OG][LORA_R];
        const int o0 = (blockIdx.x >> 2) * OG;
        if (t < OG * RANK) {
            int r8 = t / RANK, k = t % RANK;
            s_sa[r8][k] = scale_A[(o0 + r8) * RANK + k] * g[k];
        }
        if (t < OG * LORA_R) {
            int r8 = t / LORA_R, r = t % LORA_R;
            s_lb[r8][r] = lora_B[(o0 + r8) * LORA_R + r] * LORA_SCALING;
        }
        __syncthreads();

        const int i0 = ((blockIdx.x & 3) * 256 + t) * 4;

        f32x4 acc[OG];
#pragma unroll
        for (int r8 = 0; r8 < OG; ++r8) acc[r8] = {0.f, 0.f, 0.f, 0.f};
#pragma unroll
        for (int k = 0; k < RANK; ++k) {
            f32x4 sbk = *(const f32x4*)(scale_B + k * IN_DIM + i0);
#pragma unroll
            for (int r8 = 0; r8 < OG; ++r8) acc[r8] += s_sa[r8][k] * sbk;
        }
#pragma unroll
        for (int r8 = 0; r8 < OG; ++r8) {
            f32x4 wv = *(const f32x4*)(weight + (size_t)(o0 + r8) * IN_DIM + i0);
            acc[r8] *= wv;
        }
#pragma unroll
        for (int r = 0; r < LORA_R; ++r) {
            f32x4 lak = *(const f32x4*)(lora_A + r * IN_DIM + i0);
#pragma unroll
            for (int r8 = 0; r8 < OG; ++r8) acc[r8] += s_lb[r8][r] * lak;
        }
#pragma unroll
        for (int r8 = 0; r8 < OG; ++r8) {
            bf16x4 h = { (bf16)acc[r8][0], (bf16)acc[r8][1],
                         (bf16)acc[r8][2], (bf16)acc[r8][3] };
            *(bf16x4*)(wt + (size_t)(o0 + r8) * IN_DIM + i0) = h;
        }
    } else {
        const int n4  = (M_DIM * IN_DIM) / 4;
        int idx    = (blockIdx.x - 2048) * 256 + t;
        int stride = 2048 * 256;
        for (int i = idx; i < n4; i += stride) {
            f32x4 v = *(const f32x4*)(x + (size_t)i * 4);
            bf16x4 h = { (bf16)v[0], (bf16)v[1], (bf16)v[2], (bf16)v[3] };
            *(bf16x4*)(xb + (size_t)i * 4) = h;
        }
    }
}

// -------------------------------------------------------------------------
// Kernel 2: 256x256 tile, BK=64, 8 waves (2Mx4N), MFMA 16x16x32,
// LDS halves [128 rows][128B].
//
// R3 change (ONLY): full 3-bit swizzle  sigma(row, c) = c ^ (row & 7).
// R2's 1-bit XOR left lanes 0-15 of each frag-read on 2 of 8 slots ->
// ~8-way conflict (measured 1.52e7). With row&7: any aligned 16-lane
// group reads slots {0..7} exactly twice -> 2-way = free (m136).
//   - stage side: gload dest LINEAR; lane l pre-swizzles its GLOBAL
//     source chunk to (l&7) ^ ((l>>3)&7)  [row-within-wave = l>>3]
//     => LDS slot s of row r holds chunk s ^ (r&7).
//   - read side: frag (row = rb + (l&15), chunk = ks*4 + (l>>4)) read at
//     slot (ks*4 + (l>>4)) ^ (l&7).  rb multiple of 16 => r&7 == l&7.
//     ks=1 slot = slot0 ^ 4 (XOR not +64) -> two per-lane slot offsets.
//
// LDS map (bytes), buffer p at p*65536:
//   A-half h: p*65536 + h*16384,  B-half h: p*65536 + 32768 + h*16384
// Phases = global C-quadrants: ph1 (0,0), ph2 (0,1), ph3 (1,1), ph4 (1,0).
// Stage schedule (tile t+1): ph1: A-h0, ph2: B-h0, ph3: B-h1, ph4: A-h1.
// Uniform vmcnt(4) at every phase close (4 loads in flight, never 0).
// -------------------------------------------------------------------------
#define BM 256
#define BN 256
#define BK 64

__device__ __forceinline__ void gload16(const bf16* g, bf16* l) {
    __builtin_amdgcn_global_load_lds(
        (const __attribute__((address_space(1))) void*)g,
        (__attribute__((address_space(3))) void*)l,
        16, 0, 0);
}

#define BARRIER()    __builtin_amdgcn_s_barrier()
#define WAIT_LGKM0() asm volatile("s_waitcnt lgkmcnt(0)" ::: "memory")
#define WAIT_VM(n)   asm volatile("s_waitcnt vmcnt(" #n ")" ::: "memory")

__device__ __forceinline__ void load_af(bf16x8 (&aF)[4][2], const char* aB,
                                        int off, int s0, int s1) {
#pragma unroll
    for (int r = 0; r < 4; ++r) {
        aF[r][0] = *(const bf16x8*)(aB + off + r * 2048 + s0);
        aF[r][1] = *(const bf16x8*)(aB + off + r * 2048 + s1);
    }
}
__device__ __forceinline__ void load_bf(bf16x8 (&bF)[2][2], const char* bB,
                                        int off, int s0, int s1) {
#pragma unroll
    for (int n = 0; n < 2; ++n) {
        bF[n][0] = *(const bf16x8*)(bB + off + n * 2048 + s0);
        bF[n][1] = *(const bf16x8*)(bB + off + n * 2048 + s1);
    }
}

template<int QM, int QN>
__device__ __forceinline__ void mfma_quad(f32x4 (&acc)[2][2][4][2],
                                          const bf16x8 (&aF)[4][2],
                                          const bf16x8 (&bF)[2][2]) {
#pragma unroll
    for (int ks = 0; ks < 2; ++ks)
#pragma unroll
        for (int r = 0; r < 4; ++r)
#pragma unroll
            for (int n = 0; n < 2; ++n)
                acc[QM][QN][r][n] = __builtin_amdgcn_mfma_f32_16x16x32_bf16(
                    aF[r][ks], bF[n][ks], acc[QM][QN][r][n], 0, 0, 0);
}

__global__ __launch_bounds__(512, 2) void gemm_bt(
    const bf16* __restrict__ A,   // [4096,4096] bf16 row-major (x)
    const bf16* __restrict__ Bw,  // [4096,4096] bf16 row-major (W_eff, B^T)
    float* __restrict__ C)        // [4096,4096] fp32 row-major
{
    __shared__ __align__(16) char smem[131072];

    const int t  = threadIdx.x;
    const int w  = t >> 6;        // wave 0..7
    const int l  = t & 63;
    const int wm = w >> 2;        // 0..1 -> wave M offset within quadrant: wm*64
    const int wn = w & 3;         // 0..3 -> wave N offset within quadrant: wn*32

    // XCD-compact block mapping: 256 blocks = 8 XCDs x (4M x 8N) tile chunk.
    const int bid = blockIdx.x;
    const int xcd = bid & 7;
    const int loc = bid >> 3;                      // 0..31
    const int mt  = (xcd & 3) * 4 + (loc >> 3);    // 0..15
    const int nt  = (xcd >> 2) * 8 + (loc & 7);    // 0..15
    const int m0  = mt * BM;
    const int n0  = nt * BN;

    // ---- staging (per lane): wave w covers rows w*8 + (l>>3) (+64 for 2nd
    // gload). Pre-swizzled global source chunk: (l&7) ^ ((l>>3)&7).
    const int scol = 8 * ((l & 7) ^ ((l >> 3) & 7));
    const bf16* gAs = A  + (size_t)(m0 + w * 8 + (l >> 3)) * IN_DIM + scol;
    const bf16* gBs = Bw + (size_t)(n0 + w * 8 + (l >> 3)) * IN_DIM + scol;

#define STAGEH(gbase, kc, dstOff) do {                                        \
        gload16((gbase) + (kc),                                               \
                (bf16*)(smem + (dstOff) + (w << 10)));                        \
        gload16((gbase) + (kc) + (size_t)64 * IN_DIM,                         \
                (bf16*)(smem + (dstOff) + 8192 + (w << 10)));                 \
    } while (0)

    // ---- ds_read slot offsets: slot(ks) = (ks*4 + (l>>4)) ^ (l&7).
    const int fr  = l & 15;
    const int sA0 = (((l >> 4) & 3) ^ (l & 7)) << 4;
    const int sA1 = ((4 | ((l >> 4) & 3)) ^ (l & 7)) << 4;
    const char* aB = smem + wm * 8192 + fr * 128;            // + po + QM*16384
    const char* bB = smem + 32768 + wn * 4096 + fr * 128;    // + po + QN*16384

    f32x4 acc[2][2][4][2] = {};
    bf16x8 aF[4][2], bF[2][2];

    // ---- prologue: tile 0's halves in deadline order; keep last 4 in flight.
    STAGEH(gAs, 0, 0);                                   // A-h0(0)
    STAGEH(gBs, 0, 32768);                               // B-h0(0)
    STAGEH(gBs + (size_t)128 * IN_DIM, 0, 49152);        // B-h1(0)
    STAGEH(gAs + (size_t)128 * IN_DIM, 0, 16384);        // A-h1(0)
    WAIT_VM(4);
    BARRIER();

#pragma unroll 2
    for (int kt = 0; kt < 64; ++kt) {
        const int po  = (kt & 1) << 16;
        const int qo  = po ^ 65536;
        const int kcn = (kt + 1 < 64) ? (kt + 1) * BK : 0;   // clamped (bf16 cols)

        // ===== phase 1: quadrant (0,0) =====
        load_af(aF, aB, po, sA0, sA1);
        load_bf(bF, bB, po, sA0, sA1);
        STAGEH(gAs, kcn, qo);                            // A-h0(t+1)
        BARRIER();
        WAIT_LGKM0();
        __builtin_amdgcn_s_setprio(1);
        mfma_quad<0, 0>(acc, aF, bF);
        __builtin_amdgcn_s_setprio(0);
        WAIT_VM(4);
        BARRIER();

        // ===== phase 2: quadrant (0,1) — A-frags reused =====
        load_bf(bF, bB, po + 16384, sA0, sA1);
        STAGEH(gBs, kcn, qo + 32768);                    // B-h0(t+1)
        BARRIER();
        WAIT_LGKM0();
        __builtin_amdgcn_s_setprio(1);
        mfma_quad<0, 1>(acc, aF, bF);
        __builtin_amdgcn_s_setprio(0);
        WAIT_VM(4);
        BARRIER();

        // ===== phase 3: quadrant (1,1) — B-frags reused =====
        load_af(aF, aB, po + 16384, sA0, sA1);
        STAGEH(gBs + (size_t)128 * IN_DIM, kcn, qo + 49152);   // B-h1(t+1)
        BARRIER();
        WAIT_LGKM0();
        __builtin_amdgcn_s_setprio(1);
        mfma_quad<1, 1>(acc, aF, bF);
        __builtin_amdgcn_s_setprio(0);
        WAIT_VM(4);
        BARRIER();

        // ===== phase 4: quadrant (1,0) — A-frags reused =====
        load_bf(bF, bB, po, sA0, sA1);
        STAGEH(gAs + (size_t)128 * IN_DIM, kcn, qo + 16384);   // A-h1(t+1)
        BARRIER();
        WAIT_LGKM0();
        __builtin_amdgcn_s_setprio(1);
        mfma_quad<1, 0>(acc, aF, bF);
        __builtin_amdgcn_s_setprio(0);
        WAIT_VM(4);
        BARRIER();
    }

    // ---- epilogue: drain, then per-wave LDS transpose (stride 33) ----
    asm volatile("s_waitcnt vmcnt(0) lgkmcnt(0)" ::: "memory");
    BARRIER();
    float* sE = (float*)(void*)smem + w * (64 * 33);   // 8448B/wave * 8 = 67.6KB
    const int er = l >> 4;        // 0..3
    const int ec = l & 15;
#pragma unroll
    for (int QM = 0; QM < 2; ++QM)
#pragma unroll
        for (int QN = 0; QN < 2; ++QN) {
            // C/D layout (m89/m91): col = l&15, row = (l>>4)*4 + j
#pragma unroll
            for (int r = 0; r < 4; ++r)
#pragma unroll
                for (int n = 0; n < 2; ++n)
#pragma unroll
                    for (int j = 0; j < 4; ++j)
                        sE[(r * 16 + er * 4 + j) * 33 + n * 16 + ec] =
                            acc[QM][QN][r][n][j];
#pragma unroll
            for (int q = 0; q < 8; ++q) {
                int r2 = q * 8 + (l >> 3);
                int c2 = (l & 7) * 4;
                f32x4 v = { sE[r2 * 33 + c2],     sE[r2 * 33 + c2 + 1],
                            sE[r2 * 33 + c2 + 2], sE[r2 * 33 + c2 + 3] };
                *(f32x4*)(C + (size_t)(m0 + QM * 128 + wm * 64 + r2) * OUT_DIM
                            + (n0 + QN * 128 + wn * 32 + c2)) = v;
            }
        }
}

// -------------------------------------------------------------------------
extern "C" void kernel_launch(void* const* d_in, const int* in_sizes, int n_in,
                              void* d_out, int out_size, void* d_ws, size_t ws_size,
                              hipStream_t stream) {
    (void)in_sizes; (void)n_in; (void)out_size; (void)ws_size;
    const float* x        = (const float*)d_in[0];
    const float* weight   = (const float*)d_in[1];
    const float* scale_A  = (const float*)d_in[2];
    const float* scale_B  = (const float*)d_in[3];
    const float* g        = (const float*)d_in[4];
    const float* lora_A   = (const float*)d_in[5];
    const float* lora_B   = (const float*)d_in[6];
    float* out = (float*)d_out;

    bf16* xb = (bf16*)d_ws;
    bf16* wt = (bf16*)((char*)d_ws + (size_t)M_DIM * IN_DIM * sizeof(bf16));

    prep_fused<<<4096, 256, 0, stream>>>(weight, scale_A, scale_B, g,
                                         lora_A, lora_B, x, wt, xb);

    gemm_bt<<<(M_DIM / BM) * (OUT_DIM / BN), 512, 0, stream>>>(xb, wt, out);
}